// Round 21
// baseline (243.898 us; speedup 1.0000x reference)
//
#include <hip/hip_runtime.h>
#include <hip/hip_bf16.h>
#include <math.h>

#define HEADS 4
#define OUTC 40
#define SLOPE 0.2f
#define DCAP 128

typedef __attribute__((ext_vector_type(8))) short bf16x8;
typedef __attribute__((ext_vector_type(4))) float f32x4;

__device__ __forceinline__ short f2bf(float f) {
    unsigned u = __float_as_uint(f);
    unsigned r = (u + 0x7FFFu + ((u >> 16) & 1u)) >> 16;
    return (short)r;
}
__device__ __forceinline__ float bf2f(short s) {
    return __uint_as_float(((unsigned)(unsigned short)s) << 16);
}
__device__ __forceinline__ float bfu2f(unsigned short s) {
    return __uint_as_float(((unsigned)s) << 16);
}

typedef const __attribute__((address_space(1))) unsigned int gu32;
typedef __attribute__((address_space(3))) unsigned int lu32;
__device__ __forceinline__ void gll16(const void* src, void* lds) {
    __builtin_amdgcn_global_load_lds((gu32*)src, (lu32*)lds, 16, 0, 0);
}

// ---------------------------------------------------------------------------
// bf16 MFMA GEMM (R19-proven config). BN=128, BK=64, 4 waves.
// AMODE=0: A bf16 via global_load_lds. AMODE=1: A f32 reg-staged depth-1.
// FUSE=2: rows >= fy do CSR scatter+selfloop (fc2).
// XCD pair-swizzle (bijective): pair col-blocks of same A-rows on one XCD.
// ---------------------------------------------------------------------------
template<int BM_, int AMODE, int EPI, int FUSE>
__global__ __launch_bounds__(256) void gemm2(
    const float* __restrict__ Af,
    const short* __restrict__ A,
    const short* __restrict__ B,
    const float* __restrict__ bias,
    unsigned short* __restrict__ Obf, unsigned short* __restrict__ Ob2,
    float* __restrict__ Of,
    int M, int N, int K,
    const int* __restrict__ fA, const int* __restrict__ fB,
    const int* __restrict__ fC, const int* __restrict__ fD,
    int* __restrict__ fX,
    int fE, int fN, int fy)
{
    if (FUSE == 2 && (int)blockIdx.y >= fy) {
        int e = ((blockIdx.y - fy) * gridDim.x + blockIdx.x) * 256 + threadIdx.x;
        if (e < fE) {
            fX[fD[fB[e]] + fC[e]] = fA[e];               // csr[offs[dst]+rank]=src
        } else if (e < fE + fN) {
            int n = e - fE;
            fX[fD[n + 1] - 1] = n;                       // self-loop slot
        }
        return;
    }

    constexpr int MI = BM_ / 32;
    __shared__ short smem[BM_ * 64 + 8192];
    short* As = smem;
    short* Bs = smem + BM_ * 64;

    const int tid = threadIdx.x;
    const int wid = tid >> 6, lane = tid & 63;

    // ---- XCD pair-swizzle (bijective) ----
    int bn, bm;
    if (gridDim.x == 2) {
        int rows = (FUSE == 0) ? (int)gridDim.y : fy;
        int nwg  = rows * 2;
        int orig = (int)blockIdx.y * 2 + (int)blockIdx.x;
        int xcd = orig & 7;
        int q = nwg >> 3, r = nwg & 7;
        int wg = (xcd < r ? xcd * (q + 1) : r * (q + 1) + (xcd - r) * q) + (orig >> 3);
        bn = (wg & 1) * 128;
        bm = (wg >> 1) * BM_;
    } else {
        bn = blockIdx.x * 128;
        bm = blockIdx.y * BM_;
    }

    const int wm = wid >> 1, wn = wid & 1;
    const int rA = lane & 15, kb = lane >> 4;

    f32x4 acc[MI][4];
    #pragma unroll
    for (int i = 0; i < MI; i++)
        #pragma unroll
        for (int j = 0; j < 4; j++)
            acc[i][j] = (f32x4){0.f, 0.f, 0.f, 0.f};

    const int KT = K >> 6;

    const float* asrcF[BM_ / 32];
    #pragma unroll
    for (int it = 0; it < BM_ / 32; it++) {
        int g = it * 256 + tid;
        int row = g >> 3, gr = g & 7;
        int gsrc = gr ^ (row & 7);
        int grow = bm + row; if (grow > M - 1) grow = M - 1;
        asrcF[it] = AMODE ? (Af + (size_t)grow * K + gsrc * 8) : nullptr;
    }

    f32x4 pf0[BM_ / 32], pf1[BM_ / 32];        // depth-1 prefetch regs

    auto LOADA = [&](int kt) {
        #pragma unroll
        for (int it = 0; it < BM_ / 32; it++) {
            const float* s = asrcF[it] + ((size_t)kt << 6);
            pf0[it] = *(const f32x4*)s;
            pf1[it] = *(const f32x4*)(s + 4);
        }
    };
    auto STAGE_A_REG = [&]() {
        #pragma unroll
        for (int it = 0; it < BM_ / 32; it++) {
            bf16x8 v;
            v[0] = f2bf(pf0[it][0]); v[1] = f2bf(pf0[it][1]);
            v[2] = f2bf(pf0[it][2]); v[3] = f2bf(pf0[it][3]);
            v[4] = f2bf(pf1[it][0]); v[5] = f2bf(pf1[it][1]);
            v[6] = f2bf(pf1[it][2]); v[7] = f2bf(pf1[it][3]);
            *(bf16x8*)(As + (size_t)(it * 256 + tid) * 8) = v;
        }
    };
    auto STAGE_A_LDS = [&](int kt) {
        const int k0 = kt << 6;
        #pragma unroll
        for (int it = 0; it < BM_ / 32; it++) {
            int g = it * 256 + tid;
            int row = g >> 3, gr = g & 7;
            int gsrc = gr ^ (row & 7);
            int grow = bm + row; if (grow > M - 1) grow = M - 1;
            gll16(A + (size_t)grow * K + k0 + gsrc * 8,
                  As + (it * 256 + wid * 64) * 8);
        }
    };
    auto STAGE_B = [&](int kt) {
        const int k0 = kt << 6;
        #pragma unroll
        for (int it = 0; it < 4; it++) {
            int g = it * 256 + tid;
            int row = g >> 3, gr = g & 7;
            int gsrc = gr ^ (row & 7);
            gll16(B + (size_t)(bn + row) * K + k0 + gsrc * 8,
                  Bs + (it * 256 + wid * 64) * 8);
        }
    };
    auto COMPUTE = [&]() {
        #pragma unroll
        for (int kc = 0; kc < 2; kc++) {
            bf16x8 a[MI], b[4];
            #pragma unroll
            for (int mi = 0; mi < MI; mi++) {
                int r = wm * (BM_ / 2) + mi * 16 + rA;
                int off = r * 64 + (((kc * 4 + kb) ^ (r & 7)) * 8);
                a[mi] = *(const bf16x8*)(As + off);
            }
            #pragma unroll
            for (int ni = 0; ni < 4; ni++) {
                int r = wn * 64 + ni * 16 + rA;
                int off = r * 64 + (((kc * 4 + kb) ^ (r & 7)) * 8);
                b[ni] = *(const bf16x8*)(Bs + off);
            }
            #pragma unroll
            for (int mi = 0; mi < MI; mi++)
                #pragma unroll
                for (int ni = 0; ni < 4; ni++)
                    acc[mi][ni] = __builtin_amdgcn_mfma_f32_16x16x32_bf16(a[mi], b[ni], acc[mi][ni], 0, 0, 0);
        }
    };

    if (AMODE == 1) LOADA(0);
    for (int kt = 0; kt < KT; kt++) {
        if (AMODE == 0) STAGE_A_LDS(kt); else STAGE_A_REG();
        STAGE_B(kt);
        __syncthreads();
        if (AMODE == 1 && kt + 1 < KT) LOADA(kt + 1);
        COMPUTE();
        __syncthreads();
    }

    // ---- epilogue (C/D map: col=lane&15, row=(lane>>4)*4+j) ----
    #pragma unroll
    for (int ni = 0; ni < 4; ni++) {
        int col = bn + wn * 64 + ni * 16 + rA;
        float bv = (EPI == 0) ? bias[col] : 0.f;
        #pragma unroll
        for (int mi = 0; mi < MI; mi++) {
            #pragma unroll
            for (int j = 0; j < 4; j++) {
                int row = bm + wm * (BM_ / 2) + mi * 16 + kb * 4 + j;
                if (row < M) {
                    float v = acc[mi][ni][j];
                    if (EPI == 0) {
                        v = fmaxf(v + bv, 0.f);
                        Obf[(size_t)row * N + col] = (unsigned short)f2bf(v);
                    } else if (EPI == 1) {
                        if (col < 128) Obf[(size_t)row * 128 + col] = (unsigned short)f2bf(v);
                        else           Ob2[(size_t)row * 128 + (col - 128)] = (unsigned short)f2bf(v);
                    } else {
                        if (col < 80) {
                            v += bias[col];
                            Of[(size_t)row * 80 + col] = v;
                            if (col < OUTC)
                                Obf[(size_t)row * OUTC + col] = (unsigned short)f2bf(v);
                        }
                    }
                }
            }
        }
    }
}

// ---------------------------------------------------------------------------
// Fused prep: CSR count_rank (big, blocks first) + weight planes.
// count only needs dstA; runs while the GPU is otherwise idle, freeing fc1.
// ---------------------------------------------------------------------------
__global__ void prepcnt(const int* __restrict__ dstA, int E,
                        int* __restrict__ deg, int* __restrict__ rank,
                        const float* __restrict__ ae_w1, const float* __restrict__ ae_w2,
                        const float* __restrict__ g1w, const float* __restrict__ r1w,
                        const float* __restrict__ g2w, const float* __restrict__ r2w,
                        const float* __restrict__ r2b,
                        short* __restrict__ w1T, short* __restrict__ w2T,
                        short* __restrict__ wc1, short* __restrict__ wc2T,
                        float* __restrict__ cb2, int cntBlocks) {
    int b = blockIdx.x;
    if (b < cntBlocks) {
        int e = b * 256 + threadIdx.x;
        if (e < E) rank[e] = atomicAdd(&deg[dstA[e]], 1);
        return;
    }
    int gid = (b - cntBlocks) * 256 + threadIdx.x;
    if (gid < 131072) {
        int n = gid >> 9, k = gid & 511;
        w1T[gid] = f2bf(ae_w1[(size_t)k * 256 + n]);
        return;
    }
    gid -= 131072;
    if (gid < 65536) {
        int n = gid >> 8, k = gid & 255;
        w2T[gid] = f2bf(ae_w2[(size_t)k * 256 + n]);
        return;
    }
    gid -= 65536;
    if (gid < 65536) {
        int n = gid >> 8, k = gid & 255;
        float v = (n < 128) ? g1w[(size_t)k * 128 + n] : r1w[(size_t)k * 128 + (n - 128)];
        wc1[gid] = f2bf(v);
        return;
    }
    gid -= 65536;
    if (gid < 16384) {
        int n = gid >> 7, k = gid & 127;
        float v = 0.f;
        if (n < OUTC)          v = g2w[k * OUTC + n];
        else if (n < 2 * OUTC) v = r2w[k * OUTC + (n - OUTC)];
        wc2T[gid] = f2bf(v);
        return;
    }
    gid -= 16384;
    if (gid < 80) cb2[gid] = (gid < OUTC) ? 0.f : r2b[gid - OUTC];
}

// ---------------------------------------------------------------------------
// CSR scan kernels
// ---------------------------------------------------------------------------
__global__ void scan_part(const int* __restrict__ deg, int N, int* __restrict__ part) {
    __shared__ int s[256];
    int b = blockIdx.x, t = threadIdx.x;
    int i0 = b * 1024 + t * 4;
    int sum = 0;
    #pragma unroll
    for (int j = 0; j < 4; j++) { int i = i0 + j; if (i < N) sum += deg[i] + 1; }
    s[t] = sum; __syncthreads();
    for (int o = 128; o; o >>= 1) { if (t < o) s[t] += s[t + o]; __syncthreads(); }
    if (t == 0) part[b] = s[0];
}

__global__ void scan_base(int* __restrict__ part, int nb, int* __restrict__ offs) {
    int t = threadIdx.x;
    int v = (t < nb) ? part[t] : 0;
    int v0 = v;
    for (int o = 1; o < 64; o <<= 1) {
        int u = __shfl_up(v, o, 64);
        if (t >= o) v += u;
    }
    if (t < nb) part[t] = v - v0;
    if (t == 0) offs[0] = 0;
}

__global__ void scan_final(const int* __restrict__ deg, int N, const int* __restrict__ part,
                           int* __restrict__ offs) {
    __shared__ int s[256];
    int b = blockIdx.x, t = threadIdx.x;
    int i0 = b * 1024 + t * 4;
    int v[4]; int sum = 0;
    #pragma unroll
    for (int j = 0; j < 4; j++) { int i = i0 + j; v[j] = (i < N) ? deg[i] + 1 : 0; sum += v[j]; }
    s[t] = sum; __syncthreads();
    for (int o = 1; o < 256; o <<= 1) {
        int add = (t >= o) ? s[t - o] : 0;
        __syncthreads();
        s[t] += add;
        __syncthreads();
    }
    int excl = s[t] - sum + part[b];
    #pragma unroll
    for (int j = 0; j < 4; j++) {
        int i = i0 + j;
        if (i < N) { offs[i + 1] = excl + v[j]; excl += v[j]; }
    }
}

// ---------------------------------------------------------------------------
// Attention score vectors
// ---------------------------------------------------------------------------
__global__ void att1(const unsigned short* __restrict__ h1b, const float* __restrict__ atts,
                     const float* __restrict__ attd, float* __restrict__ as1,
                     float* __restrict__ ad1, int N) {
    int idx = blockIdx.x * blockDim.x + threadIdx.x;
    if (idx >= N * HEADS) return;
    int n = idx >> 2, h = idx & 3;
    const unsigned short* row = h1b + (size_t)n * 128 + h * 32;
    float ss = 0.f, dd = 0.f;
    #pragma unroll
    for (int c4 = 0; c4 < 4; c4++) {
        uint4 v = *(const uint4*)(row + c4 * 8);
        float4 ws1 = *(const float4*)(atts + h * 32 + c4 * 8);
        float4 ws2 = *(const float4*)(atts + h * 32 + c4 * 8 + 4);
        float4 wd1 = *(const float4*)(attd + h * 32 + c4 * 8);
        float4 wd2 = *(const float4*)(attd + h * 32 + c4 * 8 + 4);
        float e0 = bfu2f((unsigned short)(v.x & 0xFFFF)), e1 = bfu2f((unsigned short)(v.x >> 16));
        float e2 = bfu2f((unsigned short)(v.y & 0xFFFF)), e3 = bfu2f((unsigned short)(v.y >> 16));
        float e4 = bfu2f((unsigned short)(v.z & 0xFFFF)), e5 = bfu2f((unsigned short)(v.z >> 16));
        float e6 = bfu2f((unsigned short)(v.w & 0xFFFF)), e7 = bfu2f((unsigned short)(v.w >> 16));
        ss += e0*ws1.x + e1*ws1.y + e2*ws1.z + e3*ws1.w + e4*ws2.x + e5*ws2.y + e6*ws2.z + e7*ws2.w;
        dd += e0*wd1.x + e1*wd1.y + e2*wd1.z + e3*wd1.w + e4*wd2.x + e5*wd2.y + e6*wd2.z + e7*wd2.w;
    }
    as1[idx] = ss; ad1[idx] = dd;
}

__global__ void att2(const float* __restrict__ h2r2, const float* __restrict__ atts,
                     const float* __restrict__ attd, float* __restrict__ as2,
                     float* __restrict__ ad2, int N) {
    int n = blockIdx.x * blockDim.x + threadIdx.x;
    if (n >= N) return;
    const float* row = h2r2 + (size_t)n * 80;
    float ss = 0.f, dd = 0.f;
    #pragma unroll
    for (int c = 0; c < OUTC; c += 4) {
        float4 v = *(const float4*)(row + c);
        float4 ws = *(const float4*)(atts + c);
        float4 wd = *(const float4*)(attd + c);
        ss += v.x*ws.x + v.y*ws.y + v.z*ws.z + v.w*ws.w;
        dd += v.x*wd.x + v.y*wd.y + v.z*wd.z + v.w*wd.w;
    }
    as2[n] = ss; ad2[n] = dd;
}

// ---------------------------------------------------------------------------
// GAT1 fused softmax+aggregate (LDS score cache; DCAP fallback).
// ---------------------------------------------------------------------------
__global__ __launch_bounds__(256) void gat1_fused(const unsigned short* __restrict__ h1b,
                                                  const unsigned short* __restrict__ r1b,
                                                  const float* __restrict__ as1,
                                                  const float* __restrict__ ad1,
                                                  const int* __restrict__ offs,
                                                  const int* __restrict__ csr,
                                                  const float* __restrict__ gb,
                                                  const float* __restrict__ rb,
                                                  unsigned short* __restrict__ hbufb, int N) {
    __shared__ float sc[4][DCAP * 4];
    __shared__ int  scs[4][DCAP];
    int nl = threadIdx.x >> 6;
    int n = blockIdx.x * 4 + nl;
    if (n >= N) return;
    int t = threadIdx.x & 63;
    int h = t >> 4, l = t & 15;
    int beg = offs[n], d = offs[n + 1] - beg;
    float adst = ad1[n * 4 + h];

    float mx = -INFINITY;
    for (int j = l; j < d; j += 16) {
        int s = csr[beg + j];
        float v = as1[s * 4 + h] + adst;
        v = v >= 0.f ? v : SLOPE * v;
        if (j < DCAP) {
            sc[nl][j * 4 + h] = v;
            if (h == 0) scs[nl][j] = s;
        }
        mx = fmaxf(mx, v);
    }
    #pragma unroll
    for (int o = 8; o; o >>= 1) mx = fmaxf(mx, __shfl_xor(mx, o, 16));
    float den = 0.f;
    for (int j = l; j < d; j += 16) {
        float v;
        if (j < DCAP) v = sc[nl][j * 4 + h];
        else {
            int s = csr[beg + j];
            v = as1[s * 4 + h] + adst;
            v = v >= 0.f ? v : SLOPE * v;
        }
        den += __expf(v - mx);
    }
    #pragma unroll
    for (int o = 8; o; o >>= 1) den += __shfl_xor(den, o, 16);
    float iv = 1.f / fmaxf(den, 1e-16f);

    float acc0 = 0.f, acc1 = 0.f;
    for (int j = 0; j < d; j += 8) {
        int cs[8]; float cw[8];
        #pragma unroll
        for (int u = 0; u < 8; u++) {
            int jj = j + u;
            if (jj < d && jj < DCAP) {
                cs[u] = scs[nl][jj];
                cw[u] = __expf(sc[nl][jj * 4 + h] - mx);
            } else if (jj < d) {
                int s = csr[beg + jj];
                cs[u] = s;
                float v = as1[s * 4 + h] + adst;
                v = v >= 0.f ? v : SLOPE * v;
                cw[u] = __expf(v - mx);
            } else { cs[u] = 0; cw[u] = 0.f; }
        }
        #pragma unroll
        for (int u = 0; u < 8; u++) {
            ushort2 hv = *(const ushort2*)(h1b + (size_t)cs[u] * 128 + 2 * t);
            acc0 += cw[u] * bfu2f(hv.x);
            acc1 += cw[u] * bfu2f(hv.y);
        }
    }
    acc0 *= iv; acc1 *= iv;
    ushort2 rv = *(const ushort2*)(r1b + (size_t)n * 128 + 2 * t);
    float2 gv = *(const float2*)(gb + 2 * t);
    float2 bv = *(const float2*)(rb + 2 * t);
    float o0 = fmaxf(acc0 + gv.x + bv.x + bfu2f(rv.x), 0.f);
    float o1 = fmaxf(acc1 + gv.y + bv.y + bfu2f(rv.y), 0.f);
    ushort2 ov = {(unsigned short)f2bf(o0), (unsigned short)f2bf(o1)};
    *(ushort2*)(hbufb + (size_t)n * 128 + 2 * t) = ov;
}

// ---------------------------------------------------------------------------
// GAT2 fused softmax+aggregate.
// ---------------------------------------------------------------------------
__global__ __launch_bounds__(256) void gat2_fused(const unsigned short* __restrict__ h2b,
                                                  const float* __restrict__ h2r2,
                                                  const float* __restrict__ as2,
                                                  const float* __restrict__ ad2,
                                                  const int* __restrict__ offs,
                                                  const int* __restrict__ csr,
                                                  const float* __restrict__ gb,
                                                  float* __restrict__ out, int N) {
    __shared__ float sc[4][DCAP];
    __shared__ int  scs[4][DCAP];
    int nl = threadIdx.x >> 6;
    int n = blockIdx.x * 4 + nl;
    if (n >= N) return;
    int t = threadIdx.x & 63;
    int beg = offs[n], d = offs[n + 1] - beg;
    float adst = ad2[n];

    float mx = -INFINITY;
    for (int j = t; j < d; j += 64) {
        int s = csr[beg + j];
        float v = as2[s] + adst;
        v = v >= 0.f ? v : SLOPE * v;
        if (j < DCAP) { sc[nl][j] = v; scs[nl][j] = s; }
        mx = fmaxf(mx, v);
    }
    #pragma unroll
    for (int o = 32; o; o >>= 1) mx = fmaxf(mx, __shfl_xor(mx, o, 64));
    float den = 0.f;
    for (int j = t; j < d; j += 64) {
        float v;
        if (j < DCAP) v = sc[nl][j];
        else {
            int s = csr[beg + j];
            v = as2[s] + adst;
            v = v >= 0.f ? v : SLOPE * v;
        }
        den += __expf(v - mx);
    }
    #pragma unroll
    for (int o = 32; o; o >>= 1) den += __shfl_xor(den, o, 64);
    float iv = 1.f / fmaxf(den, 1e-16f);

    float acc0 = 0.f, acc1 = 0.f;
    for (int j = 0; j < d; j += 8) {
        int cs[8]; float cw[8];
        #pragma unroll
        for (int u = 0; u < 8; u++) {
            int jj = j + u;
            if (jj < d && jj < DCAP) {
                cs[u] = scs[nl][jj];
                cw[u] = __expf(sc[nl][jj] - mx);
            } else if (jj < d) {
                int s = csr[beg + jj];
                cs[u] = s;
                float v = as2[s] + adst;
                v = v >= 0.f ? v : SLOPE * v;
                cw[u] = __expf(v - mx);
            } else { cs[u] = 0; cw[u] = 0.f; }
        }
        if (t < 20) {
            #pragma unroll
            for (int u = 0; u < 8; u++) {
                ushort2 hv = *(const ushort2*)(h2b + (size_t)cs[u] * OUTC + 2 * t);
                acc0 += cw[u] * bfu2f(hv.x);
                acc1 += cw[u] * bfu2f(hv.y);
            }
        }
    }
    if (t < 20) {
        float2 rr = *(const float2*)(h2r2 + (size_t)n * 80 + 40 + 2 * t);
        float2 gv = *(const float2*)(gb + 2 * t);
        float2 ov = {acc0 * iv + gv.x + rr.x, acc1 * iv + gv.y + rr.y};
        *(float2*)(out + (size_t)n * OUTC + 2 * t) = ov;
    }
}

// ---------------------------------------------------------------------------
// Launcher
// ---------------------------------------------------------------------------
extern "C" void kernel_launch(void* const* d_in, const int* in_sizes, int n_in,
                              void* d_out, int out_size, void* d_ws, size_t ws_size,
                              hipStream_t stream) {
    const float* x      = (const float*)d_in[0];
    const int*   ei     = (const int*)d_in[1];
    const float* ae_w1  = (const float*)d_in[2];
    const float* ae_b1  = (const float*)d_in[3];
    const float* ae_w2  = (const float*)d_in[4];
    const float* ae_b2  = (const float*)d_in[5];
    const float* gat1_w = (const float*)d_in[6];
    const float* g1as   = (const float*)d_in[7];
    const float* g1ad   = (const float*)d_in[8];
    const float* g1b    = (const float*)d_in[9];
    const float* gat2_w = (const float*)d_in[10];
    const float* g2as   = (const float*)d_in[11];
    const float* g2ad   = (const float*)d_in[12];
    const float* g2b    = (const float*)d_in[13];
    const float* res1_w = (const float*)d_in[14];
    const float* res1_b = (const float*)d_in[15];
    const float* res2_w = (const float*)d_in[16];
    const float* res2_b = (const float*)d_in[17];
    float* out = (float*)d_out;

    const int Nn = in_sizes[0] / 512;       // 50000 nodes
    const int E  = in_sizes[1] / 2;         // 800000 edges
    const int Etot = E + Nn;

    const int* srcA = ei;
    const int* dstA = ei + E;

    // ---- workspace layout ----
    char* W = (char*)d_ws;
    size_t off = 0;
    auto alloc = [&](size_t bytes) { char* p = W + off; off += (bytes + 255) & ~(size_t)255; return p; };

    unsigned short* y1b   = (unsigned short*)alloc((size_t)Nn * 256 * 2);
    unsigned short* xeb   = (unsigned short*)alloc((size_t)Nn * 256 * 2);
    unsigned short* h1b   = (unsigned short*)alloc((size_t)Nn * 128 * 2);
    unsigned short* r1b   = (unsigned short*)alloc((size_t)Nn * 128 * 2);
    unsigned short* hbufb = (unsigned short*)alloc((size_t)Nn * 128 * 2);
    float*          h2r2  = (float*)alloc((size_t)Nn * 80 * 4);
    unsigned short* h2bf  = (unsigned short*)alloc((size_t)Nn * OUTC * 2);

    short* w1T  = (short*)alloc(256 * 512 * 2);
    short* w2T  = (short*)alloc(256 * 256 * 2);
    short* wc1  = (short*)alloc(256 * 256 * 2);
    short* wc2T = (short*)alloc(128 * 128 * 2);
    float* cb2  = (float*)alloc(80 * 4);
    float* as1  = (float*)alloc((size_t)Nn * HEADS * 4);
    float* ad1  = (float*)alloc((size_t)Nn * HEADS * 4);
    float* as2  = (float*)alloc((size_t)Nn * 4);
    float* ad2  = (float*)alloc((size_t)Nn * 4);
    int* deg  = (int*)alloc((size_t)Nn * 4);
    int* offs = (int*)alloc((size_t)(Nn + 1) * 4);
    int* rank = (int*)alloc((size_t)E * 4);
    int* part = (int*)alloc(256 * 4);
    int* csr  = (int*)alloc((size_t)Etot * 4);

    // ---- prep: deg clear, then fused count_rank + weight planes ----
    hipMemsetAsync(deg, 0, (size_t)Nn * sizeof(int), stream);
    {
        int cntBlocks = (E + 255) / 256;
        int wtotal = 131072 + 65536 + 65536 + 16384 + 80;
        int wBlocks = (wtotal + 255) / 256;
        prepcnt<<<cntBlocks + wBlocks, 256, 0, stream>>>(
            dstA, E, deg, rank,
            ae_w1, ae_w2, gat1_w, res1_w, gat2_w, res2_w, res2_b,
            w1T, w2T, wc1, wc2T, cb2, cntBlocks);
    }

    const int gy1 = (Nn + 31) / 32;                 // fc1 rows (BM=32)
    const int gy2 = (Nn + 63) / 64;                 // others (BM=64)
    const int scatRows = (E + Nn + 511) / 512;

    // ---- fc1 (BM=32, reg-staged depth-1, XCD pair-swizzle; no fused tail) ----
    gemm2<32, 1, 0, 0><<<dim3(2, gy1), 256, 0, stream>>>(
        x, nullptr, w1T, ae_b1, y1b, nullptr, nullptr, Nn, 256, 512,
        nullptr, nullptr, nullptr, nullptr, nullptr, 0, 0, 0);

    // ---- CSR scan ----
    int nb = (Nn + 1023) / 1024;
    scan_part<<<nb, 256, 0, stream>>>(deg, Nn, part);
    scan_base<<<1, 64, 0, stream>>>(part, nb, offs);
    scan_final<<<nb, 256, 0, stream>>>(deg, Nn, part, offs);

    // ---- fc2 (BM=64, gll16) + FUSED scatter+selfloop ----
    gemm2<64, 0, 0, 2><<<dim3(2, gy2 + scatRows), 256, 0, stream>>>(
        nullptr, (const short*)y1b, w2T, ae_b2, xeb, nullptr, nullptr, Nn, 256, 256,
        srcA, dstA, rank, offs, csr, E, Nn, gy2);

    // ---- gatres1 (BM=64, gll16) ----
    gemm2<64, 0, 1, 0><<<dim3(2, gy2), 256, 0, stream>>>(
        nullptr, (const short*)xeb, wc1, nullptr, h1b, r1b, nullptr, Nn, 256, 256,
        nullptr, nullptr, nullptr, nullptr, nullptr, 0, 0, 0);

    // ---- layer-1 attention (fused maxden+agg) ----
    att1<<<(Nn * HEADS + 255) / 256, 256, 0, stream>>>(h1b, g1as, g1ad, as1, ad1, Nn);
    gat1_fused<<<(Nn + 3) / 4, 256, 0, stream>>>(h1b, r1b, as1, ad1, offs, csr, g1b, res1_b, hbufb, Nn);

    // ---- gatres2 (bf16 MFMA, zero-padded N) ----
    gemm2<64, 0, 2, 0><<<dim3(1, gy2), 256, 0, stream>>>(
        nullptr, (const short*)hbufb, wc2T, cb2, h2bf, nullptr, h2r2, Nn, 128, 128,
        nullptr, nullptr, nullptr, nullptr, nullptr, 0, 0, 0);

    // ---- layer-2 attention (fused) ----
    att2<<<(Nn + 255) / 256, 256, 0, stream>>>(h2r2, g2as, g2ad, as2, ad2, Nn);
    gat2_fused<<<(Nn + 3) / 4, 256, 0, stream>>>(h2bf, h2r2, as2, ad2, offs, csr, g2b, out, Nn);
}

// Round 22
// 233.333 us; speedup vs baseline: 1.0453x; 1.0453x over previous
//
#include <hip/hip_runtime.h>
#include <hip/hip_bf16.h>
#include <math.h>

#define HEADS 4
#define OUTC 40
#define SLOPE 0.2f
#define DCAP 128

typedef __attribute__((ext_vector_type(8))) short bf16x8;
typedef __attribute__((ext_vector_type(4))) float f32x4;

__device__ __forceinline__ short f2bf(float f) {
    unsigned u = __float_as_uint(f);
    unsigned r = (u + 0x7FFFu + ((u >> 16) & 1u)) >> 16;
    return (short)r;
}
__device__ __forceinline__ float bf2f(short s) {
    return __uint_as_float(((unsigned)(unsigned short)s) << 16);
}
__device__ __forceinline__ float bfu2f(unsigned short s) {
    return __uint_as_float(((unsigned)s) << 16);
}

typedef const __attribute__((address_space(1))) unsigned int gu32;
typedef __attribute__((address_space(3))) unsigned int lu32;
__device__ __forceinline__ void gll16(const void* src, void* lds) {
    __builtin_amdgcn_global_load_lds((gu32*)src, (lu32*)lds, 16, 0, 0);
}

// ---------------------------------------------------------------------------
// bf16 MFMA GEMM, templated on BM_/AMODE/EPI/FUSE (R19-proven best config).
// AMODE=0: A bf16 [M,K] via global_load_lds. AMODE=1: A f32 reg-staged,
// depth-1 pipeline. FUSE=1: rows >= fy do CSR count_rank (overlaps under the
// stall-bound GEMM). FUSE=2: rows >= fy do scatter+selfloop.
// XCD pair-swizzle (bijective): pair col-blocks of same A-rows on one XCD
// -> second A-read is an L2 hit (FETCH halved, measured R19).
// ---------------------------------------------------------------------------
template<int BM_, int AMODE, int EPI, int FUSE>
__global__ __launch_bounds__(256) void gemm2(
    const float* __restrict__ Af,
    const short* __restrict__ A,
    const short* __restrict__ B,
    const float* __restrict__ bias,
    unsigned short* __restrict__ Obf, unsigned short* __restrict__ Ob2,
    float* __restrict__ Of,
    int M, int N, int K,
    const int* __restrict__ fA, const int* __restrict__ fB,
    const int* __restrict__ fC, const int* __restrict__ fD,
    int* __restrict__ fX, int* __restrict__ fY_,
    int fE, int fN, int fy)
{
    if (FUSE == 1 && (int)blockIdx.y >= fy) {
        int e = ((blockIdx.y - fy) * gridDim.x + blockIdx.x) * 256 + threadIdx.x;
        if (e < fE) fY_[e] = atomicAdd(&fX[fA[e]], 1);   // rank-capture count
        return;
    }
    if (FUSE == 2 && (int)blockIdx.y >= fy) {
        int e = ((blockIdx.y - fy) * gridDim.x + blockIdx.x) * 256 + threadIdx.x;
        if (e < fE) {
            fX[fD[fB[e]] + fC[e]] = fA[e];               // csr[offs[dst]+rank]=src
        } else if (e < fE + fN) {
            int n = e - fE;
            fX[fD[n + 1] - 1] = n;                       // self-loop slot
        }
        return;
    }

    constexpr int MI = BM_ / 32;
    __shared__ short smem[BM_ * 64 + 8192];
    short* As = smem;
    short* Bs = smem + BM_ * 64;

    const int tid = threadIdx.x;
    const int wid = tid >> 6, lane = tid & 63;

    // ---- XCD pair-swizzle (bijective) ----
    int bn, bm;
    if (gridDim.x == 2) {
        int rows = (FUSE == 0) ? (int)gridDim.y : fy;
        int nwg  = rows * 2;
        int orig = (int)blockIdx.y * 2 + (int)blockIdx.x;
        int xcd = orig & 7;
        int q = nwg >> 3, r = nwg & 7;
        int wg = (xcd < r ? xcd * (q + 1) : r * (q + 1) + (xcd - r) * q) + (orig >> 3);
        bn = (wg & 1) * 128;
        bm = (wg >> 1) * BM_;
    } else {
        bn = blockIdx.x * 128;
        bm = blockIdx.y * BM_;
    }

    const int wm = wid >> 1, wn = wid & 1;
    const int rA = lane & 15, kb = lane >> 4;

    f32x4 acc[MI][4];
    #pragma unroll
    for (int i = 0; i < MI; i++)
        #pragma unroll
        for (int j = 0; j < 4; j++)
            acc[i][j] = (f32x4){0.f, 0.f, 0.f, 0.f};

    const int KT = K >> 6;

    const float* asrcF[BM_ / 32];
    #pragma unroll
    for (int it = 0; it < BM_ / 32; it++) {
        int g = it * 256 + tid;
        int row = g >> 3, gr = g & 7;
        int gsrc = gr ^ (row & 7);
        int grow = bm + row; if (grow > M - 1) grow = M - 1;
        asrcF[it] = AMODE ? (Af + (size_t)grow * K + gsrc * 8) : nullptr;
    }

    f32x4 pf0[BM_ / 32], pf1[BM_ / 32];        // depth-1 prefetch regs

    auto LOADA = [&](int kt) {
        #pragma unroll
        for (int it = 0; it < BM_ / 32; it++) {
            const float* s = asrcF[it] + ((size_t)kt << 6);
            pf0[it] = *(const f32x4*)s;
            pf1[it] = *(const f32x4*)(s + 4);
        }
    };
    auto STAGE_A_REG = [&]() {
        #pragma unroll
        for (int it = 0; it < BM_ / 32; it++) {
            bf16x8 v;
            v[0] = f2bf(pf0[it][0]); v[1] = f2bf(pf0[it][1]);
            v[2] = f2bf(pf0[it][2]); v[3] = f2bf(pf0[it][3]);
            v[4] = f2bf(pf1[it][0]); v[5] = f2bf(pf1[it][1]);
            v[6] = f2bf(pf1[it][2]); v[7] = f2bf(pf1[it][3]);
            *(bf16x8*)(As + (size_t)(it * 256 + tid) * 8) = v;
        }
    };
    auto STAGE_A_LDS = [&](int kt) {
        const int k0 = kt << 6;
        #pragma unroll
        for (int it = 0; it < BM_ / 32; it++) {
            int g = it * 256 + tid;
            int row = g >> 3, gr = g & 7;
            int gsrc = gr ^ (row & 7);
            int grow = bm + row; if (grow > M - 1) grow = M - 1;
            gll16(A + (size_t)grow * K + k0 + gsrc * 8,
                  As + (it * 256 + wid * 64) * 8);
        }
    };
    auto STAGE_B = [&](int kt) {
        const int k0 = kt << 6;
        #pragma unroll
        for (int it = 0; it < 4; it++) {
            int g = it * 256 + tid;
            int row = g >> 3, gr = g & 7;
            int gsrc = gr ^ (row & 7);
            gll16(B + (size_t)(bn + row) * K + k0 + gsrc * 8,
                  Bs + (it * 256 + wid * 64) * 8);
        }
    };
    auto COMPUTE = [&]() {
        #pragma unroll
        for (int kc = 0; kc < 2; kc++) {
            bf16x8 a[MI], b[4];
            #pragma unroll
            for (int mi = 0; mi < MI; mi++) {
                int r = wm * (BM_ / 2) + mi * 16 + rA;
                int off = r * 64 + (((kc * 4 + kb) ^ (r & 7)) * 8);
                a[mi] = *(const bf16x8*)(As + off);
            }
            #pragma unroll
            for (int ni = 0; ni < 4; ni++) {
                int r = wn * 64 + ni * 16 + rA;
                int off = r * 64 + (((kc * 4 + kb) ^ (r & 7)) * 8);
                b[ni] = *(const bf16x8*)(Bs + off);
            }
            #pragma unroll
            for (int mi = 0; mi < MI; mi++)
                #pragma unroll
                for (int ni = 0; ni < 4; ni++)
                    acc[mi][ni] = __builtin_amdgcn_mfma_f32_16x16x32_bf16(a[mi], b[ni], acc[mi][ni], 0, 0, 0);
        }
    };

    if (AMODE == 1) LOADA(0);
    for (int kt = 0; kt < KT; kt++) {
        if (AMODE == 0) STAGE_A_LDS(kt); else STAGE_A_REG();
        STAGE_B(kt);
        __syncthreads();
        if (AMODE == 1 && kt + 1 < KT) LOADA(kt + 1);
        COMPUTE();
        __syncthreads();
    }

    // ---- epilogue (C/D map: col=lane&15, row=(lane>>4)*4+j) ----
    #pragma unroll
    for (int ni = 0; ni < 4; ni++) {
        int col = bn + wn * 64 + ni * 16 + rA;
        float bv = (EPI == 0) ? bias[col] : 0.f;
        #pragma unroll
        for (int mi = 0; mi < MI; mi++) {
            #pragma unroll
            for (int j = 0; j < 4; j++) {
                int row = bm + wm * (BM_ / 2) + mi * 16 + kb * 4 + j;
                if (row < M) {
                    float v = acc[mi][ni][j];
                    if (EPI == 0) {
                        v = fmaxf(v + bv, 0.f);
                        Obf[(size_t)row * N + col] = (unsigned short)f2bf(v);
                    } else if (EPI == 1) {
                        if (col < 128) Obf[(size_t)row * 128 + col] = (unsigned short)f2bf(v);
                        else           Ob2[(size_t)row * 128 + (col - 128)] = (unsigned short)f2bf(v);
                    } else {
                        if (col < 80) {
                            v += bias[col];
                            Of[(size_t)row * 80 + col] = v;
                            if (col < OUTC)
                                Obf[(size_t)row * OUTC + col] = (unsigned short)f2bf(v);
                        }
                    }
                }
            }
        }
    }
}

// ---------------------------------------------------------------------------
// Fused weight prep
// ---------------------------------------------------------------------------
__global__ void wprep(const float* __restrict__ ae_w1, const float* __restrict__ ae_w2,
                      const float* __restrict__ g1w, const float* __restrict__ r1w,
                      const float* __restrict__ g2w, const float* __restrict__ r2w,
                      const float* __restrict__ r2b,
                      short* __restrict__ w1T, short* __restrict__ w2T,
                      short* __restrict__ wc1, short* __restrict__ wc2T,
                      float* __restrict__ cb2) {
    int gid = blockIdx.x * blockDim.x + threadIdx.x;
    if (gid < 131072) {
        int n = gid >> 9, k = gid & 511;
        w1T[gid] = f2bf(ae_w1[(size_t)k * 256 + n]);
        return;
    }
    gid -= 131072;
    if (gid < 65536) {
        int n = gid >> 8, k = gid & 255;
        w2T[gid] = f2bf(ae_w2[(size_t)k * 256 + n]);
        return;
    }
    gid -= 65536;
    if (gid < 65536) {
        int n = gid >> 8, k = gid & 255;
        float v = (n < 128) ? g1w[(size_t)k * 128 + n] : r1w[(size_t)k * 128 + (n - 128)];
        wc1[gid] = f2bf(v);
        return;
    }
    gid -= 65536;
    if (gid < 16384) {
        int n = gid >> 7, k = gid & 127;
        float v = 0.f;
        if (n < OUTC)          v = g2w[k * OUTC + n];
        else if (n < 2 * OUTC) v = r2w[k * OUTC + (n - OUTC)];
        wc2T[gid] = f2bf(v);
        return;
    }
    gid -= 16384;
    if (gid < 80) cb2[gid] = (gid < OUTC) ? 0.f : r2b[gid - OUTC];
}

// ---------------------------------------------------------------------------
// CSR scan kernels
// ---------------------------------------------------------------------------
__global__ void scan_part(const int* __restrict__ deg, int N, int* __restrict__ part) {
    __shared__ int s[256];
    int b = blockIdx.x, t = threadIdx.x;
    int i0 = b * 1024 + t * 4;
    int sum = 0;
    #pragma unroll
    for (int j = 0; j < 4; j++) { int i = i0 + j; if (i < N) sum += deg[i] + 1; }
    s[t] = sum; __syncthreads();
    for (int o = 128; o; o >>= 1) { if (t < o) s[t] += s[t + o]; __syncthreads(); }
    if (t == 0) part[b] = s[0];
}

__global__ void scan_base(int* __restrict__ part, int nb, int* __restrict__ offs) {
    int t = threadIdx.x;
    int v = (t < nb) ? part[t] : 0;
    int v0 = v;
    for (int o = 1; o < 64; o <<= 1) {
        int u = __shfl_up(v, o, 64);
        if (t >= o) v += u;
    }
    if (t < nb) part[t] = v - v0;
    if (t == 0) offs[0] = 0;
}

__global__ void scan_final(const int* __restrict__ deg, int N, const int* __restrict__ part,
                           int* __restrict__ offs) {
    __shared__ int s[256];
    int b = blockIdx.x, t = threadIdx.x;
    int i0 = b * 1024 + t * 4;
    int v[4]; int sum = 0;
    #pragma unroll
    for (int j = 0; j < 4; j++) { int i = i0 + j; v[j] = (i < N) ? deg[i] + 1 : 0; sum += v[j]; }
    s[t] = sum; __syncthreads();
    for (int o = 1; o < 256; o <<= 1) {
        int add = (t >= o) ? s[t - o] : 0;
        __syncthreads();
        s[t] += add;
        __syncthreads();
    }
    int excl = s[t] - sum + part[b];
    #pragma unroll
    for (int j = 0; j < 4; j++) {
        int i = i0 + j;
        if (i < N) { offs[i + 1] = excl + v[j]; excl += v[j]; }
    }
}

// ---------------------------------------------------------------------------
// Attention score vectors
// ---------------------------------------------------------------------------
__global__ void att1(const unsigned short* __restrict__ h1b, const float* __restrict__ atts,
                     const float* __restrict__ attd, float* __restrict__ as1,
                     float* __restrict__ ad1, int N) {
    int idx = blockIdx.x * blockDim.x + threadIdx.x;
    if (idx >= N * HEADS) return;
    int n = idx >> 2, h = idx & 3;
    const unsigned short* row = h1b + (size_t)n * 128 + h * 32;
    float ss = 0.f, dd = 0.f;
    #pragma unroll
    for (int c4 = 0; c4 < 4; c4++) {
        uint4 v = *(const uint4*)(row + c4 * 8);
        float4 ws1 = *(const float4*)(atts + h * 32 + c4 * 8);
        float4 ws2 = *(const float4*)(atts + h * 32 + c4 * 8 + 4);
        float4 wd1 = *(const float4*)(attd + h * 32 + c4 * 8);
        float4 wd2 = *(const float4*)(attd + h * 32 + c4 * 8 + 4);
        float e0 = bfu2f((unsigned short)(v.x & 0xFFFF)), e1 = bfu2f((unsigned short)(v.x >> 16));
        float e2 = bfu2f((unsigned short)(v.y & 0xFFFF)), e3 = bfu2f((unsigned short)(v.y >> 16));
        float e4 = bfu2f((unsigned short)(v.z & 0xFFFF)), e5 = bfu2f((unsigned short)(v.z >> 16));
        float e6 = bfu2f((unsigned short)(v.w & 0xFFFF)), e7 = bfu2f((unsigned short)(v.w >> 16));
        ss += e0*ws1.x + e1*ws1.y + e2*ws1.z + e3*ws1.w + e4*ws2.x + e5*ws2.y + e6*ws2.z + e7*ws2.w;
        dd += e0*wd1.x + e1*wd1.y + e2*wd1.z + e3*wd1.w + e4*wd2.x + e5*wd2.y + e6*wd2.z + e7*wd2.w;
    }
    as1[idx] = ss; ad1[idx] = dd;
}

__global__ void att2(const float* __restrict__ h2r2, const float* __restrict__ atts,
                     const float* __restrict__ attd, float* __restrict__ as2,
                     float* __restrict__ ad2, int N) {
    int n = blockIdx.x * blockDim.x + threadIdx.x;
    if (n >= N) return;
    const float* row = h2r2 + (size_t)n * 80;
    float ss = 0.f, dd = 0.f;
    #pragma unroll
    for (int c = 0; c < OUTC; c += 4) {
        float4 v = *(const float4*)(row + c);
        float4 ws = *(const float4*)(atts + c);
        float4 wd = *(const float4*)(attd + c);
        ss += v.x*ws.x + v.y*ws.y + v.z*ws.z + v.w*ws.w;
        dd += v.x*wd.x + v.y*wd.y + v.z*wd.z + v.w*wd.w;
    }
    as2[n] = ss; ad2[n] = dd;
}

// ---------------------------------------------------------------------------
// GAT1 fused softmax+aggregate (LDS score cache; DCAP fallback).
// ---------------------------------------------------------------------------
__global__ __launch_bounds__(256) void gat1_fused(const unsigned short* __restrict__ h1b,
                                                  const unsigned short* __restrict__ r1b,
                                                  const float* __restrict__ as1,
                                                  const float* __restrict__ ad1,
                                                  const int* __restrict__ offs,
                                                  const int* __restrict__ csr,
                                                  const float* __restrict__ gb,
                                                  const float* __restrict__ rb,
                                                  unsigned short* __restrict__ hbufb, int N) {
    __shared__ float sc[4][DCAP * 4];
    __shared__ int  scs[4][DCAP];
    int nl = threadIdx.x >> 6;
    int n = blockIdx.x * 4 + nl;
    if (n >= N) return;
    int t = threadIdx.x & 63;
    int h = t >> 4, l = t & 15;
    int beg = offs[n], d = offs[n + 1] - beg;
    float adst = ad1[n * 4 + h];

    float mx = -INFINITY;
    for (int j = l; j < d; j += 16) {
        int s = csr[beg + j];
        float v = as1[s * 4 + h] + adst;
        v = v >= 0.f ? v : SLOPE * v;
        if (j < DCAP) {
            sc[nl][j * 4 + h] = v;
            if (h == 0) scs[nl][j] = s;
        }
        mx = fmaxf(mx, v);
    }
    #pragma unroll
    for (int o = 8; o; o >>= 1) mx = fmaxf(mx, __shfl_xor(mx, o, 16));
    float den = 0.f;
    for (int j = l; j < d; j += 16) {
        float v;
        if (j < DCAP) v = sc[nl][j * 4 + h];
        else {
            int s = csr[beg + j];
            v = as1[s * 4 + h] + adst;
            v = v >= 0.f ? v : SLOPE * v;
        }
        den += __expf(v - mx);
    }
    #pragma unroll
    for (int o = 8; o; o >>= 1) den += __shfl_xor(den, o, 16);
    float iv = 1.f / fmaxf(den, 1e-16f);

    float acc0 = 0.f, acc1 = 0.f;
    for (int j = 0; j < d; j += 8) {
        int cs[8]; float cw[8];
        #pragma unroll
        for (int u = 0; u < 8; u++) {
            int jj = j + u;
            if (jj < d && jj < DCAP) {
                cs[u] = scs[nl][jj];
                cw[u] = __expf(sc[nl][jj * 4 + h] - mx);
            } else if (jj < d) {
                int s = csr[beg + jj];
                cs[u] = s;
                float v = as1[s * 4 + h] + adst;
                v = v >= 0.f ? v : SLOPE * v;
                cw[u] = __expf(v - mx);
            } else { cs[u] = 0; cw[u] = 0.f; }
        }
        #pragma unroll
        for (int u = 0; u < 8; u++) {
            ushort2 hv = *(const ushort2*)(h1b + (size_t)cs[u] * 128 + 2 * t);
            acc0 += cw[u] * bfu2f(hv.x);
            acc1 += cw[u] * bfu2f(hv.y);
        }
    }
    acc0 *= iv; acc1 *= iv;
    ushort2 rv = *(const ushort2*)(r1b + (size_t)n * 128 + 2 * t);
    float2 gv = *(const float2*)(gb + 2 * t);
    float2 bv = *(const float2*)(rb + 2 * t);
    float o0 = fmaxf(acc0 + gv.x + bv.x + bfu2f(rv.x), 0.f);
    float o1 = fmaxf(acc1 + gv.y + bv.y + bfu2f(rv.y), 0.f);
    ushort2 ov = {(unsigned short)f2bf(o0), (unsigned short)f2bf(o1)};
    *(ushort2*)(hbufb + (size_t)n * 128 + 2 * t) = ov;
}

// ---------------------------------------------------------------------------
// GAT2 fused softmax+aggregate.
// ---------------------------------------------------------------------------
__global__ __launch_bounds__(256) void gat2_fused(const unsigned short* __restrict__ h2b,
                                                  const float* __restrict__ h2r2,
                                                  const float* __restrict__ as2,
                                                  const float* __restrict__ ad2,
                                                  const int* __restrict__ offs,
                                                  const int* __restrict__ csr,
                                                  const float* __restrict__ gb,
                                                  float* __restrict__ out, int N) {
    __shared__ float sc[4][DCAP];
    __shared__ int  scs[4][DCAP];
    int nl = threadIdx.x >> 6;
    int n = blockIdx.x * 4 + nl;
    if (n >= N) return;
    int t = threadIdx.x & 63;
    int beg = offs[n], d = offs[n + 1] - beg;
    float adst = ad2[n];

    float mx = -INFINITY;
    for (int j = t; j < d; j += 64) {
        int s = csr[beg + j];
        float v = as2[s] + adst;
        v = v >= 0.f ? v : SLOPE * v;
        if (j < DCAP) { sc[nl][j] = v; scs[nl][j] = s; }
        mx = fmaxf(mx, v);
    }
    #pragma unroll
    for (int o = 32; o; o >>= 1) mx = fmaxf(mx, __shfl_xor(mx, o, 64));
    float den = 0.f;
    for (int j = t; j < d; j += 64) {
        float v;
        if (j < DCAP) v = sc[nl][j];
        else {
            int s = csr[beg + j];
            v = as2[s] + adst;
            v = v >= 0.f ? v : SLOPE * v;
        }
        den += __expf(v - mx);
    }
    #pragma unroll
    for (int o = 32; o; o >>= 1) den += __shfl_xor(den, o, 64);
    float iv = 1.f / fmaxf(den, 1e-16f);

    float acc0 = 0.f, acc1 = 0.f;
    for (int j = 0; j < d; j += 8) {
        int cs[8]; float cw[8];
        #pragma unroll
        for (int u = 0; u < 8; u++) {
            int jj = j + u;
            if (jj < d && jj < DCAP) {
                cs[u] = scs[nl][jj];
                cw[u] = __expf(sc[nl][jj] - mx);
            } else if (jj < d) {
                int s = csr[beg + jj];
                cs[u] = s;
                float v = as2[s] + adst;
                v = v >= 0.f ? v : SLOPE * v;
                cw[u] = __expf(v - mx);
            } else { cs[u] = 0; cw[u] = 0.f; }
        }
        if (t < 20) {
            #pragma unroll
            for (int u = 0; u < 8; u++) {
                ushort2 hv = *(const ushort2*)(h2b + (size_t)cs[u] * OUTC + 2 * t);
                acc0 += cw[u] * bfu2f(hv.x);
                acc1 += cw[u] * bfu2f(hv.y);
            }
        }
    }
    if (t < 20) {
        float2 rr = *(const float2*)(h2r2 + (size_t)n * 80 + 40 + 2 * t);
        float2 gv = *(const float2*)(gb + 2 * t);
        float2 ov = {acc0 * iv + gv.x + rr.x, acc1 * iv + gv.y + rr.y};
        *(float2*)(out + (size_t)n * OUTC + 2 * t) = ov;
    }
}

// ---------------------------------------------------------------------------
// Launcher
// ---------------------------------------------------------------------------
extern "C" void kernel_launch(void* const* d_in, const int* in_sizes, int n_in,
                              void* d_out, int out_size, void* d_ws, size_t ws_size,
                              hipStream_t stream) {
    const float* x      = (const float*)d_in[0];
    const int*   ei     = (const int*)d_in[1];
    const float* ae_w1  = (const float*)d_in[2];
    const float* ae_b1  = (const float*)d_in[3];
    const float* ae_w2  = (const float*)d_in[4];
    const float* ae_b2  = (const float*)d_in[5];
    const float* gat1_w = (const float*)d_in[6];
    const float* g1as   = (const float*)d_in[7];
    const float* g1ad   = (const float*)d_in[8];
    const float* g1b    = (const float*)d_in[9];
    const float* gat2_w = (const float*)d_in[10];
    const float* g2as   = (const float*)d_in[11];
    const float* g2ad   = (const float*)d_in[12];
    const float* g2b    = (const float*)d_in[13];
    const float* res1_w = (const float*)d_in[14];
    const float* res1_b = (const float*)d_in[15];
    const float* res2_w = (const float*)d_in[16];
    const float* res2_b = (const float*)d_in[17];
    float* out = (float*)d_out;

    const int Nn = in_sizes[0] / 512;       // 50000 nodes
    const int E  = in_sizes[1] / 2;         // 800000 edges
    const int Etot = E + Nn;

    const int* srcA = ei;
    const int* dstA = ei + E;

    // ---- workspace layout ----
    char* W = (char*)d_ws;
    size_t off = 0;
    auto alloc = [&](size_t bytes) { char* p = W + off; off += (bytes + 255) & ~(size_t)255; return p; };

    unsigned short* y1b   = (unsigned short*)alloc((size_t)Nn * 256 * 2);
    unsigned short* xeb   = (unsigned short*)alloc((size_t)Nn * 256 * 2);
    unsigned short* h1b   = (unsigned short*)alloc((size_t)Nn * 128 * 2);
    unsigned short* r1b   = (unsigned short*)alloc((size_t)Nn * 128 * 2);
    unsigned short* hbufb = (unsigned short*)alloc((size_t)Nn * 128 * 2);
    float*          h2r2  = (float*)alloc((size_t)Nn * 80 * 4);
    unsigned short* h2bf  = (unsigned short*)alloc((size_t)Nn * OUTC * 2);

    short* w1T  = (short*)alloc(256 * 512 * 2);
    short* w2T  = (short*)alloc(256 * 256 * 2);
    short* wc1  = (short*)alloc(256 * 256 * 2);
    short* wc2T = (short*)alloc(128 * 128 * 2);
    float* cb2  = (float*)alloc(80 * 4);
    float* as1  = (float*)alloc((size_t)Nn * HEADS * 4);
    float* ad1  = (float*)alloc((size_t)Nn * HEADS * 4);
    float* as2  = (float*)alloc((size_t)Nn * 4);
    float* ad2  = (float*)alloc((size_t)Nn * 4);
    int* deg  = (int*)alloc((size_t)Nn * 4);
    int* offs = (int*)alloc((size_t)(Nn + 1) * 4);
    int* rank = (int*)alloc((size_t)E * 4);
    int* part = (int*)alloc(256 * 4);
    int* csr  = (int*)alloc((size_t)Etot * 4);

    // ---- weight prep + deg clear ----
    {
        int total = 131072 + 65536 + 65536 + 16384 + 80;
        wprep<<<(total + 255) / 256, 256, 0, stream>>>(
            ae_w1, ae_w2, gat1_w, res1_w, gat2_w, res2_w, res2_b,
            w1T, w2T, wc1, wc2T, cb2);
    }
    hipMemsetAsync(deg, 0, (size_t)Nn * sizeof(int), stream);

    const int gy1 = (Nn + 31) / 32;                 // fc1 rows (BM=32)
    const int gy2 = (Nn + 63) / 64;                 // others (BM=64)
    const int cntRows  = (E + 511) / 512;
    const int scatRows = (E + Nn + 511) / 512;

    // ---- fc1 (BM=32, reg-staged depth-1) + FUSED count_rank ----
    gemm2<32, 1, 0, 1><<<dim3(2, gy1 + cntRows), 256, 0, stream>>>(
        x, nullptr, w1T, ae_b1, y1b, nullptr, nullptr, Nn, 256, 512,
        dstA, nullptr, nullptr, nullptr, deg, rank, E, 0, gy1);

    // ---- CSR scan ----
    int nb = (Nn + 1023) / 1024;
    scan_part<<<nb, 256, 0, stream>>>(deg, Nn, part);
    scan_base<<<1, 64, 0, stream>>>(part, nb, offs);
    scan_final<<<nb, 256, 0, stream>>>(deg, Nn, part, offs);

    // ---- fc2 (BM=64, gll16) + FUSED scatter+selfloop ----
    gemm2<64, 0, 0, 2><<<dim3(2, gy2 + scatRows), 256, 0, stream>>>(
        nullptr, (const short*)y1b, w2T, ae_b2, xeb, nullptr, nullptr, Nn, 256, 256,
        srcA, dstA, rank, offs, csr, nullptr, E, Nn, gy2);

    // ---- gatres1 (BM=64, gll16) ----
    gemm2<64, 0, 1, 0><<<dim3(2, gy2), 256, 0, stream>>>(
        nullptr, (const short*)xeb, wc1, nullptr, h1b, r1b, nullptr, Nn, 256, 256,
        nullptr, nullptr, nullptr, nullptr, nullptr, nullptr, 0, 0, 0);

    // ---- layer-1 attention (fused maxden+agg) ----
    att1<<<(Nn * HEADS + 255) / 256, 256, 0, stream>>>(h1b, g1as, g1ad, as1, ad1, Nn);
    gat1_fused<<<(Nn + 3) / 4, 256, 0, stream>>>(h1b, r1b, as1, ad1, offs, csr, g1b, res1_b, hbufb, Nn);

    // ---- gatres2 (bf16 MFMA, zero-padded N) ----
    gemm2<64, 0, 2, 0><<<dim3(1, gy2), 256, 0, stream>>>(
        nullptr, (const short*)hbufb, wc2T, cb2, h2bf, nullptr, h2r2, Nn, 128, 128,
        nullptr, nullptr, nullptr, nullptr, nullptr, nullptr, 0, 0, 0);

    // ---- layer-2 attention (fused) ----
    att2<<<(Nn + 255) / 256, 256, 0, stream>>>(h2r2, g2as, g2ad, as2, ad2, Nn);
    gat2_fused<<<(Nn + 3) / 4, 256, 0, stream>>>(h2bf, h2r2, as2, ad2, offs, csr, g2b, out, Nn);
}

// Round 23
// 231.885 us; speedup vs baseline: 1.0518x; 1.0062x over previous
//
#include <hip/hip_runtime.h>
#include <hip/hip_bf16.h>
#include <math.h>

#define HEADS 4
#define OUTC 40
#define SLOPE 0.2f
#define DCAP 128

typedef __attribute__((ext_vector_type(8))) short bf16x8;
typedef __attribute__((ext_vector_type(4))) float f32x4;

__device__ __forceinline__ short f2bf(float f) {
    unsigned u = __float_as_uint(f);
    unsigned r = (u + 0x7FFFu + ((u >> 16) & 1u)) >> 16;
    return (short)r;
}
__device__ __forceinline__ float bf2f(short s) {
    return __uint_as_float(((unsigned)(unsigned short)s) << 16);
}
__device__ __forceinline__ float bfu2f(unsigned short s) {
    return __uint_as_float(((unsigned)s) << 16);
}

typedef const __attribute__((address_space(1))) unsigned int gu32;
typedef __attribute__((address_space(3))) unsigned int lu32;
__device__ __forceinline__ void gll16(const void* src, void* lds) {
    __builtin_amdgcn_global_load_lds((gu32*)src, (lu32*)lds, 16, 0, 0);
}

// ---------------------------------------------------------------------------
// bf16 MFMA GEMM, templated on BM_/AMODE/EPI/FUSE (R19-proven best config).
// AMODE=0: A bf16 [M,K] via global_load_lds. AMODE=1: A f32 reg-staged,
// depth-1 pipeline. FUSE=1: rows >= fy do CSR count_rank (overlaps under the
// stall-bound GEMM). FUSE=2: rows >= fy do scatter+selfloop starting at fOff
// (tail split across fc2 and gatres1).
// XCD pair-swizzle (bijective): pair col-blocks of same A-rows on one XCD.
// ---------------------------------------------------------------------------
template<int BM_, int AMODE, int EPI, int FUSE>
__global__ __launch_bounds__(256) void gemm2(
    const float* __restrict__ Af,
    const short* __restrict__ A,
    const short* __restrict__ B,
    const float* __restrict__ bias,
    unsigned short* __restrict__ Obf, unsigned short* __restrict__ Ob2,
    float* __restrict__ Of,
    int M, int N, int K,
    const int* __restrict__ fA, const int* __restrict__ fB,
    const int* __restrict__ fC, const int* __restrict__ fD,
    int* __restrict__ fX, int* __restrict__ fY_,
    int fE, int fN, int fy, int fOff)
{
    if (FUSE == 1 && (int)blockIdx.y >= fy) {
        int e = ((blockIdx.y - fy) * gridDim.x + blockIdx.x) * 256 + threadIdx.x;
        if (e < fE) fY_[e] = atomicAdd(&fX[fA[e]], 1);   // rank-capture count
        return;
    }
    if (FUSE == 2 && (int)blockIdx.y >= fy) {
        int e = fOff + ((blockIdx.y - fy) * gridDim.x + blockIdx.x) * 256 + threadIdx.x;
        if (e < fE) {
            fX[fD[fB[e]] + fC[e]] = fA[e];               // csr[offs[dst]+rank]=src
        } else if (e < fE + fN) {
            int n = e - fE;
            fX[fD[n + 1] - 1] = n;                       // self-loop slot
        }
        return;
    }

    constexpr int MI = BM_ / 32;
    __shared__ short smem[BM_ * 64 + 8192];
    short* As = smem;
    short* Bs = smem + BM_ * 64;

    const int tid = threadIdx.x;
    const int wid = tid >> 6, lane = tid & 63;

    // ---- XCD pair-swizzle (bijective) ----
    int bn, bm;
    if (gridDim.x == 2) {
        int rows = (FUSE == 0) ? (int)gridDim.y : fy;
        int nwg  = rows * 2;
        int orig = (int)blockIdx.y * 2 + (int)blockIdx.x;
        int xcd = orig & 7;
        int q = nwg >> 3, r = nwg & 7;
        int wg = (xcd < r ? xcd * (q + 1) : r * (q + 1) + (xcd - r) * q) + (orig >> 3);
        bn = (wg & 1) * 128;
        bm = (wg >> 1) * BM_;
    } else {
        bn = blockIdx.x * 128;
        bm = blockIdx.y * BM_;
    }

    const int wm = wid >> 1, wn = wid & 1;
    const int rA = lane & 15, kb = lane >> 4;

    f32x4 acc[MI][4];
    #pragma unroll
    for (int i = 0; i < MI; i++)
        #pragma unroll
        for (int j = 0; j < 4; j++)
            acc[i][j] = (f32x4){0.f, 0.f, 0.f, 0.f};

    const int KT = K >> 6;

    const float* asrcF[BM_ / 32];
    #pragma unroll
    for (int it = 0; it < BM_ / 32; it++) {
        int g = it * 256 + tid;
        int row = g >> 3, gr = g & 7;
        int gsrc = gr ^ (row & 7);
        int grow = bm + row; if (grow > M - 1) grow = M - 1;
        asrcF[it] = AMODE ? (Af + (size_t)grow * K + gsrc * 8) : nullptr;
    }

    f32x4 pf0[BM_ / 32], pf1[BM_ / 32];        // depth-1 prefetch regs

    auto LOADA = [&](int kt) {
        #pragma unroll
        for (int it = 0; it < BM_ / 32; it++) {
            const float* s = asrcF[it] + ((size_t)kt << 6);
            pf0[it] = *(const f32x4*)s;
            pf1[it] = *(const f32x4*)(s + 4);
        }
    };
    auto STAGE_A_REG = [&]() {
        #pragma unroll
        for (int it = 0; it < BM_ / 32; it++) {
            bf16x8 v;
            v[0] = f2bf(pf0[it][0]); v[1] = f2bf(pf0[it][1]);
            v[2] = f2bf(pf0[it][2]); v[3] = f2bf(pf0[it][3]);
            v[4] = f2bf(pf1[it][0]); v[5] = f2bf(pf1[it][1]);
            v[6] = f2bf(pf1[it][2]); v[7] = f2bf(pf1[it][3]);
            *(bf16x8*)(As + (size_t)(it * 256 + tid) * 8) = v;
        }
    };
    auto STAGE_A_LDS = [&](int kt) {
        const int k0 = kt << 6;
        #pragma unroll
        for (int it = 0; it < BM_ / 32; it++) {
            int g = it * 256 + tid;
            int row = g >> 3, gr = g & 7;
            int gsrc = gr ^ (row & 7);
            int grow = bm + row; if (grow > M - 1) grow = M - 1;
            gll16(A + (size_t)grow * K + k0 + gsrc * 8,
                  As + (it * 256 + wid * 64) * 8);
        }
    };
    auto STAGE_B = [&](int kt) {
        const int k0 = kt << 6;
        #pragma unroll
        for (int it = 0; it < 4; it++) {
            int g = it * 256 + tid;
            int row = g >> 3, gr = g & 7;
            int gsrc = gr ^ (row & 7);
            gll16(B + (size_t)(bn + row) * K + k0 + gsrc * 8,
                  Bs + (it * 256 + wid * 64) * 8);
        }
    };
    auto COMPUTE = [&]() {
        #pragma unroll
        for (int kc = 0; kc < 2; kc++) {
            bf16x8 a[MI], b[4];
            #pragma unroll
            for (int mi = 0; mi < MI; mi++) {
                int r = wm * (BM_ / 2) + mi * 16 + rA;
                int off = r * 64 + (((kc * 4 + kb) ^ (r & 7)) * 8);
                a[mi] = *(const bf16x8*)(As + off);
            }
            #pragma unroll
            for (int ni = 0; ni < 4; ni++) {
                int r = wn * 64 + ni * 16 + rA;
                int off = r * 64 + (((kc * 4 + kb) ^ (r & 7)) * 8);
                b[ni] = *(const bf16x8*)(Bs + off);
            }
            #pragma unroll
            for (int mi = 0; mi < MI; mi++)
                #pragma unroll
                for (int ni = 0; ni < 4; ni++)
                    acc[mi][ni] = __builtin_amdgcn_mfma_f32_16x16x32_bf16(a[mi], b[ni], acc[mi][ni], 0, 0, 0);
        }
    };

    if (AMODE == 1) LOADA(0);
    for (int kt = 0; kt < KT; kt++) {
        if (AMODE == 0) STAGE_A_LDS(kt); else STAGE_A_REG();
        STAGE_B(kt);
        __syncthreads();
        if (AMODE == 1 && kt + 1 < KT) LOADA(kt + 1);
        COMPUTE();
        __syncthreads();
    }

    // ---- epilogue (C/D map: col=lane&15, row=(lane>>4)*4+j) ----
    #pragma unroll
    for (int ni = 0; ni < 4; ni++) {
        int col = bn + wn * 64 + ni * 16 + rA;
        float bv = (EPI == 0) ? bias[col] : 0.f;
        #pragma unroll
        for (int mi = 0; mi < MI; mi++) {
            #pragma unroll
            for (int j = 0; j < 4; j++) {
                int row = bm + wm * (BM_ / 2) + mi * 16 + kb * 4 + j;
                if (row < M) {
                    float v = acc[mi][ni][j];
                    if (EPI == 0) {
                        v = fmaxf(v + bv, 0.f);
                        Obf[(size_t)row * N + col] = (unsigned short)f2bf(v);
                    } else if (EPI == 1) {
                        if (col < 128) Obf[(size_t)row * 128 + col] = (unsigned short)f2bf(v);
                        else           Ob2[(size_t)row * 128 + (col - 128)] = (unsigned short)f2bf(v);
                    } else {
                        if (col < 80) {
                            v += bias[col];
                            Of[(size_t)row * 80 + col] = v;
                            if (col < OUTC)
                                Obf[(size_t)row * OUTC + col] = (unsigned short)f2bf(v);
                        }
                    }
                }
            }
        }
    }
}

// ---------------------------------------------------------------------------
// Fused weight prep + deg clear (deg-clear blocks appended; removes memset).
// ---------------------------------------------------------------------------
__global__ void wprep(const float* __restrict__ ae_w1, const float* __restrict__ ae_w2,
                      const float* __restrict__ g1w, const float* __restrict__ r1w,
                      const float* __restrict__ g2w, const float* __restrict__ r2w,
                      const float* __restrict__ r2b,
                      short* __restrict__ w1T, short* __restrict__ w2T,
                      short* __restrict__ wc1, short* __restrict__ wc2T,
                      float* __restrict__ cb2,
                      int* __restrict__ deg, int Nn, int wBlocks) {
    if ((int)blockIdx.x >= wBlocks) {
        int i = (blockIdx.x - wBlocks) * 256 + threadIdx.x;
        if (i < Nn) deg[i] = 0;
        return;
    }
    int gid = blockIdx.x * blockDim.x + threadIdx.x;
    if (gid < 131072) {
        int n = gid >> 9, k = gid & 511;
        w1T[gid] = f2bf(ae_w1[(size_t)k * 256 + n]);
        return;
    }
    gid -= 131072;
    if (gid < 65536) {
        int n = gid >> 8, k = gid & 255;
        w2T[gid] = f2bf(ae_w2[(size_t)k * 256 + n]);
        return;
    }
    gid -= 65536;
    if (gid < 65536) {
        int n = gid >> 8, k = gid & 255;
        float v = (n < 128) ? g1w[(size_t)k * 128 + n] : r1w[(size_t)k * 128 + (n - 128)];
        wc1[gid] = f2bf(v);
        return;
    }
    gid -= 65536;
    if (gid < 16384) {
        int n = gid >> 7, k = gid & 127;
        float v = 0.f;
        if (n < OUTC)          v = g2w[k * OUTC + n];
        else if (n < 2 * OUTC) v = r2w[k * OUTC + (n - OUTC)];
        wc2T[gid] = f2bf(v);
        return;
    }
    gid -= 16384;
    if (gid < 80) cb2[gid] = (gid < OUTC) ? 0.f : r2b[gid - OUTC];
}

// ---------------------------------------------------------------------------
// CSR scan kernels
// ---------------------------------------------------------------------------
__global__ void scan_part(const int* __restrict__ deg, int N, int* __restrict__ part) {
    __shared__ int s[256];
    int b = blockIdx.x, t = threadIdx.x;
    int i0 = b * 1024 + t * 4;
    int sum = 0;
    #pragma unroll
    for (int j = 0; j < 4; j++) { int i = i0 + j; if (i < N) sum += deg[i] + 1; }
    s[t] = sum; __syncthreads();
    for (int o = 128; o; o >>= 1) { if (t < o) s[t] += s[t + o]; __syncthreads(); }
    if (t == 0) part[b] = s[0];
}

__global__ void scan_base(int* __restrict__ part, int nb, int* __restrict__ offs) {
    int t = threadIdx.x;
    int v = (t < nb) ? part[t] : 0;
    int v0 = v;
    for (int o = 1; o < 64; o <<= 1) {
        int u = __shfl_up(v, o, 64);
        if (t >= o) v += u;
    }
    if (t < nb) part[t] = v - v0;
    if (t == 0) offs[0] = 0;
}

__global__ void scan_final(const int* __restrict__ deg, int N, const int* __restrict__ part,
                           int* __restrict__ offs) {
    __shared__ int s[256];
    int b = blockIdx.x, t = threadIdx.x;
    int i0 = b * 1024 + t * 4;
    int v[4]; int sum = 0;
    #pragma unroll
    for (int j = 0; j < 4; j++) { int i = i0 + j; v[j] = (i < N) ? deg[i] + 1 : 0; sum += v[j]; }
    s[t] = sum; __syncthreads();
    for (int o = 1; o < 256; o <<= 1) {
        int add = (t >= o) ? s[t - o] : 0;
        __syncthreads();
        s[t] += add;
        __syncthreads();
    }
    int excl = s[t] - sum + part[b];
    #pragma unroll
    for (int j = 0; j < 4; j++) {
        int i = i0 + j;
        if (i < N) { offs[i + 1] = excl + v[j]; excl += v[j]; }
    }
}

// ---------------------------------------------------------------------------
// Attention score vectors
// ---------------------------------------------------------------------------
__global__ void att1(const unsigned short* __restrict__ h1b, const float* __restrict__ atts,
                     const float* __restrict__ attd, float* __restrict__ as1,
                     float* __restrict__ ad1, int N) {
    int idx = blockIdx.x * blockDim.x + threadIdx.x;
    if (idx >= N * HEADS) return;
    int n = idx >> 2, h = idx & 3;
    const unsigned short* row = h1b + (size_t)n * 128 + h * 32;
    float ss = 0.f, dd = 0.f;
    #pragma unroll
    for (int c4 = 0; c4 < 4; c4++) {
        uint4 v = *(const uint4*)(row + c4 * 8);
        float4 ws1 = *(const float4*)(atts + h * 32 + c4 * 8);
        float4 ws2 = *(const float4*)(atts + h * 32 + c4 * 8 + 4);
        float4 wd1 = *(const float4*)(attd + h * 32 + c4 * 8);
        float4 wd2 = *(const float4*)(attd + h * 32 + c4 * 8 + 4);
        float e0 = bfu2f((unsigned short)(v.x & 0xFFFF)), e1 = bfu2f((unsigned short)(v.x >> 16));
        float e2 = bfu2f((unsigned short)(v.y & 0xFFFF)), e3 = bfu2f((unsigned short)(v.y >> 16));
        float e4 = bfu2f((unsigned short)(v.z & 0xFFFF)), e5 = bfu2f((unsigned short)(v.z >> 16));
        float e6 = bfu2f((unsigned short)(v.w & 0xFFFF)), e7 = bfu2f((unsigned short)(v.w >> 16));
        ss += e0*ws1.x + e1*ws1.y + e2*ws1.z + e3*ws1.w + e4*ws2.x + e5*ws2.y + e6*ws2.z + e7*ws2.w;
        dd += e0*wd1.x + e1*wd1.y + e2*wd1.z + e3*wd1.w + e4*wd2.x + e5*wd2.y + e6*wd2.z + e7*wd2.w;
    }
    as1[idx] = ss; ad1[idx] = dd;
}

__global__ void att2(const float* __restrict__ h2r2, const float* __restrict__ atts,
                     const float* __restrict__ attd, float* __restrict__ as2,
                     float* __restrict__ ad2, int N) {
    int n = blockIdx.x * blockDim.x + threadIdx.x;
    if (n >= N) return;
    const float* row = h2r2 + (size_t)n * 80;
    float ss = 0.f, dd = 0.f;
    #pragma unroll
    for (int c = 0; c < OUTC; c += 4) {
        float4 v = *(const float4*)(row + c);
        float4 ws = *(const float4*)(atts + c);
        float4 wd = *(const float4*)(attd + c);
        ss += v.x*ws.x + v.y*ws.y + v.z*ws.z + v.w*ws.w;
        dd += v.x*wd.x + v.y*wd.y + v.z*wd.z + v.w*wd.w;
    }
    as2[n] = ss; ad2[n] = dd;
}

// ---------------------------------------------------------------------------
// GAT1 fused softmax+aggregate (LDS score cache; DCAP fallback).
// ---------------------------------------------------------------------------
__global__ __launch_bounds__(256) void gat1_fused(const unsigned short* __restrict__ h1b,
                                                  const unsigned short* __restrict__ r1b,
                                                  const float* __restrict__ as1,
                                                  const float* __restrict__ ad1,
                                                  const int* __restrict__ offs,
                                                  const int* __restrict__ csr,
                                                  const float* __restrict__ gb,
                                                  const float* __restrict__ rb,
                                                  unsigned short* __restrict__ hbufb, int N) {
    __shared__ float sc[4][DCAP * 4];
    __shared__ int  scs[4][DCAP];
    int nl = threadIdx.x >> 6;
    int n = blockIdx.x * 4 + nl;
    if (n >= N) return;
    int t = threadIdx.x & 63;
    int h = t >> 4, l = t & 15;
    int beg = offs[n], d = offs[n + 1] - beg;
    float adst = ad1[n * 4 + h];

    float mx = -INFINITY;
    for (int j = l; j < d; j += 16) {
        int s = csr[beg + j];
        float v = as1[s * 4 + h] + adst;
        v = v >= 0.f ? v : SLOPE * v;
        if (j < DCAP) {
            sc[nl][j * 4 + h] = v;
            if (h == 0) scs[nl][j] = s;
        }
        mx = fmaxf(mx, v);
    }
    #pragma unroll
    for (int o = 8; o; o >>= 1) mx = fmaxf(mx, __shfl_xor(mx, o, 16));
    float den = 0.f;
    for (int j = l; j < d; j += 16) {
        float v;
        if (j < DCAP) v = sc[nl][j * 4 + h];
        else {
            int s = csr[beg + j];
            v = as1[s * 4 + h] + adst;
            v = v >= 0.f ? v : SLOPE * v;
        }
        den += __expf(v - mx);
    }
    #pragma unroll
    for (int o = 8; o; o >>= 1) den += __shfl_xor(den, o, 16);
    float iv = 1.f / fmaxf(den, 1e-16f);

    float acc0 = 0.f, acc1 = 0.f;
    for (int j = 0; j < d; j += 8) {
        int cs[8]; float cw[8];
        #pragma unroll
        for (int u = 0; u < 8; u++) {
            int jj = j + u;
            if (jj < d && jj < DCAP) {
                cs[u] = scs[nl][jj];
                cw[u] = __expf(sc[nl][jj * 4 + h] - mx);
            } else if (jj < d) {
                int s = csr[beg + jj];
                cs[u] = s;
                float v = as1[s * 4 + h] + adst;
                v = v >= 0.f ? v : SLOPE * v;
                cw[u] = __expf(v - mx);
            } else { cs[u] = 0; cw[u] = 0.f; }
        }
        #pragma unroll
        for (int u = 0; u < 8; u++) {
            ushort2 hv = *(const ushort2*)(h1b + (size_t)cs[u] * 128 + 2 * t);
            acc0 += cw[u] * bfu2f(hv.x);
            acc1 += cw[u] * bfu2f(hv.y);
        }
    }
    acc0 *= iv; acc1 *= iv;
    ushort2 rv = *(const ushort2*)(r1b + (size_t)n * 128 + 2 * t);
    float2 gv = *(const float2*)(gb + 2 * t);
    float2 bv = *(const float2*)(rb + 2 * t);
    float o0 = fmaxf(acc0 + gv.x + bv.x + bfu2f(rv.x), 0.f);
    float o1 = fmaxf(acc1 + gv.y + bv.y + bfu2f(rv.y), 0.f);
    ushort2 ov = {(unsigned short)f2bf(o0), (unsigned short)f2bf(o1)};
    *(ushort2*)(hbufb + (size_t)n * 128 + 2 * t) = ov;
}

// ---------------------------------------------------------------------------
// GAT2 fused softmax+aggregate.
// ---------------------------------------------------------------------------
__global__ __launch_bounds__(256) void gat2_fused(const unsigned short* __restrict__ h2b,
                                                  const float* __restrict__ h2r2,
                                                  const float* __restrict__ as2,
                                                  const float* __restrict__ ad2,
                                                  const int* __restrict__ offs,
                                                  const int* __restrict__ csr,
                                                  const float* __restrict__ gb,
                                                  float* __restrict__ out, int N) {
    __shared__ float sc[4][DCAP];
    __shared__ int  scs[4][DCAP];
    int nl = threadIdx.x >> 6;
    int n = blockIdx.x * 4 + nl;
    if (n >= N) return;
    int t = threadIdx.x & 63;
    int beg = offs[n], d = offs[n + 1] - beg;
    float adst = ad2[n];

    float mx = -INFINITY;
    for (int j = t; j < d; j += 64) {
        int s = csr[beg + j];
        float v = as2[s] + adst;
        v = v >= 0.f ? v : SLOPE * v;
        if (j < DCAP) { sc[nl][j] = v; scs[nl][j] = s; }
        mx = fmaxf(mx, v);
    }
    #pragma unroll
    for (int o = 32; o; o >>= 1) mx = fmaxf(mx, __shfl_xor(mx, o, 64));
    float den = 0.f;
    for (int j = t; j < d; j += 64) {
        float v;
        if (j < DCAP) v = sc[nl][j];
        else {
            int s = csr[beg + j];
            v = as2[s] + adst;
            v = v >= 0.f ? v : SLOPE * v;
        }
        den += __expf(v - mx);
    }
    #pragma unroll
    for (int o = 32; o; o >>= 1) den += __shfl_xor(den, o, 64);
    float iv = 1.f / fmaxf(den, 1e-16f);

    float acc0 = 0.f, acc1 = 0.f;
    for (int j = 0; j < d; j += 8) {
        int cs[8]; float cw[8];
        #pragma unroll
        for (int u = 0; u < 8; u++) {
            int jj = j + u;
            if (jj < d && jj < DCAP) {
                cs[u] = scs[nl][jj];
                cw[u] = __expf(sc[nl][jj] - mx);
            } else if (jj < d) {
                int s = csr[beg + jj];
                cs[u] = s;
                float v = as2[s] + adst;
                v = v >= 0.f ? v : SLOPE * v;
                cw[u] = __expf(v - mx);
            } else { cs[u] = 0; cw[u] = 0.f; }
        }
        if (t < 20) {
            #pragma unroll
            for (int u = 0; u < 8; u++) {
                ushort2 hv = *(const ushort2*)(h2b + (size_t)cs[u] * OUTC + 2 * t);
                acc0 += cw[u] * bfu2f(hv.x);
                acc1 += cw[u] * bfu2f(hv.y);
            }
        }
    }
    if (t < 20) {
        float2 rr = *(const float2*)(h2r2 + (size_t)n * 80 + 40 + 2 * t);
        float2 gv = *(const float2*)(gb + 2 * t);
        float2 ov = {acc0 * iv + gv.x + rr.x, acc1 * iv + gv.y + rr.y};
        *(float2*)(out + (size_t)n * OUTC + 2 * t) = ov;
    }
}

// ---------------------------------------------------------------------------
// Launcher
// ---------------------------------------------------------------------------
extern "C" void kernel_launch(void* const* d_in, const int* in_sizes, int n_in,
                              void* d_out, int out_size, void* d_ws, size_t ws_size,
                              hipStream_t stream) {
    const float* x      = (const float*)d_in[0];
    const int*   ei     = (const int*)d_in[1];
    const float* ae_w1  = (const float*)d_in[2];
    const float* ae_b1  = (const float*)d_in[3];
    const float* ae_w2  = (const float*)d_in[4];
    const float* ae_b2  = (const float*)d_in[5];
    const float* gat1_w = (const float*)d_in[6];
    const float* g1as   = (const float*)d_in[7];
    const float* g1ad   = (const float*)d_in[8];
    const float* g1b    = (const float*)d_in[9];
    const float* gat2_w = (const float*)d_in[10];
    const float* g2as   = (const float*)d_in[11];
    const float* g2ad   = (const float*)d_in[12];
    const float* g2b    = (const float*)d_in[13];
    const float* res1_w = (const float*)d_in[14];
    const float* res1_b = (const float*)d_in[15];
    const float* res2_w = (const float*)d_in[16];
    const float* res2_b = (const float*)d_in[17];
    float* out = (float*)d_out;

    const int Nn = in_sizes[0] / 512;       // 50000 nodes
    const int E  = in_sizes[1] / 2;         // 800000 edges
    const int Etot = E + Nn;

    const int* srcA = ei;
    const int* dstA = ei + E;

    // ---- workspace layout ----
    char* W = (char*)d_ws;
    size_t off = 0;
    auto alloc = [&](size_t bytes) { char* p = W + off; off += (bytes + 255) & ~(size_t)255; return p; };

    unsigned short* y1b   = (unsigned short*)alloc((size_t)Nn * 256 * 2);
    unsigned short* xeb   = (unsigned short*)alloc((size_t)Nn * 256 * 2);
    unsigned short* h1b   = (unsigned short*)alloc((size_t)Nn * 128 * 2);
    unsigned short* r1b   = (unsigned short*)alloc((size_t)Nn * 128 * 2);
    unsigned short* hbufb = (unsigned short*)alloc((size_t)Nn * 128 * 2);
    float*          h2r2  = (float*)alloc((size_t)Nn * 80 * 4);
    unsigned short* h2bf  = (unsigned short*)alloc((size_t)Nn * OUTC * 2);

    short* w1T  = (short*)alloc(256 * 512 * 2);
    short* w2T  = (short*)alloc(256 * 256 * 2);
    short* wc1  = (short*)alloc(256 * 256 * 2);
    short* wc2T = (short*)alloc(128 * 128 * 2);
    float* cb2  = (float*)alloc(80 * 4);
    float* as1  = (float*)alloc((size_t)Nn * HEADS * 4);
    float* ad1  = (float*)alloc((size_t)Nn * HEADS * 4);
    float* as2  = (float*)alloc((size_t)Nn * 4);
    float* ad2  = (float*)alloc((size_t)Nn * 4);
    int* deg  = (int*)alloc((size_t)Nn * 4);
    int* offs = (int*)alloc((size_t)(Nn + 1) * 4);
    int* rank = (int*)alloc((size_t)E * 4);
    int* part = (int*)alloc(256 * 4);
    int* csr  = (int*)alloc((size_t)Etot * 4);

    // ---- weight prep + deg clear (one launch) ----
    {
        int wtotal = 131072 + 65536 + 65536 + 16384 + 80;
        int wBlocks = (wtotal + 255) / 256;
        int dBlocks = (Nn + 255) / 256;
        wprep<<<wBlocks + dBlocks, 256, 0, stream>>>(
            ae_w1, ae_w2, gat1_w, res1_w, gat2_w, res2_w, res2_b,
            w1T, w2T, wc1, wc2T, cb2, deg, Nn, wBlocks);
    }

    const int gy1 = (Nn + 31) / 32;                 // fc1 rows (BM=32)
    const int gy2 = (Nn + 63) / 64;                 // others (BM=64)
    const int cntRows = (E + 511) / 512;

    // scatter tail split: half under fc2, half under gatres1
    const int scatTotal = E + Nn;
    const int scatRowsAll = (scatTotal + 511) / 512;
    const int scatRows1 = scatRowsAll / 2;
    const int scatOff   = scatRows1 * 512;
    const int scatRows2 = (scatTotal - scatOff + 511) / 512;

    // ---- fc1 (BM=32, reg-staged depth-1) + FUSED count_rank ----
    gemm2<32, 1, 0, 1><<<dim3(2, gy1 + cntRows), 256, 0, stream>>>(
        x, nullptr, w1T, ae_b1, y1b, nullptr, nullptr, Nn, 256, 512,
        dstA, nullptr, nullptr, nullptr, deg, rank, E, 0, gy1, 0);

    // ---- CSR scan ----
    int nb = (Nn + 1023) / 1024;
    scan_part<<<nb, 256, 0, stream>>>(deg, Nn, part);
    scan_base<<<1, 64, 0, stream>>>(part, nb, offs);
    scan_final<<<nb, 256, 0, stream>>>(deg, Nn, part, offs);

    // ---- fc2 (BM=64, gll16) + FUSED scatter half 1 ----
    gemm2<64, 0, 0, 2><<<dim3(2, gy2 + scatRows1), 256, 0, stream>>>(
        nullptr, (const short*)y1b, w2T, ae_b2, xeb, nullptr, nullptr, Nn, 256, 256,
        srcA, dstA, rank, offs, csr, nullptr, E, Nn, gy2, 0);

    // ---- gatres1 (BM=64, gll16) + FUSED scatter half 2 ----
    gemm2<64, 0, 1, 2><<<dim3(2, gy2 + scatRows2), 256, 0, stream>>>(
        nullptr, (const short*)xeb, wc1, nullptr, h1b, r1b, nullptr, Nn, 256, 256,
        srcA, dstA, rank, offs, csr, nullptr, E, Nn, gy2, scatOff);

    // ---- layer-1 attention (fused maxden+agg) ----
    att1<<<(Nn * HEADS + 255) / 256, 256, 0, stream>>>(h1b, g1as, g1ad, as1, ad1, Nn);
    gat1_fused<<<(Nn + 3) / 4, 256, 0, stream>>>(h1b, r1b, as1, ad1, offs, csr, g1b, res1_b, hbufb, Nn);

    // ---- gatres2 (bf16 MFMA, zero-padded N) ----
    gemm2<64, 0, 2, 0><<<dim3(1, gy2), 256, 0, stream>>>(
        nullptr, (const short*)hbufb, wc2T, cb2, h2bf, nullptr, h2r2, Nn, 128, 128,
        nullptr, nullptr, nullptr, nullptr, nullptr, nullptr, 0, 0, 0, 0);

    // ---- layer-2 attention (fused) ----
    att2<<<(Nn + 255) / 256, 256, 0, stream>>>(h2r2, g2as, g2ad, as2, ad2, Nn);
    gat2_fused<<<(Nn + 3) / 4, 256, 0, stream>>>(h2bf, h2r2, as2, ad2, offs, csr, g2b, out, Nn);
}